// Round 1
// baseline (2837.109 us; speedup 1.0000x reference)
//
#include <hip/hip_runtime.h>
#include <cstdint>
#include <cstddef>

// Problem constants (fixed instance).
constexpr int N       = 100000;     // neurons
constexpr int NNZ     = 6400000;    // edges
constexpr int B       = 8;          // batch
constexpr int T       = 8;          // timesteps
constexpr int S       = 5000;       // sensory neurons
constexpr int BIN_BITS = 7;
constexpr int BIN     = 1 << BIN_BITS;               // 128 rows per bin
constexpr int NBINS   = (N + BIN - 1) / BIN;         // 782
constexpr int CHUNK   = 16384;                       // edges per sort block
constexpr int NCHUNKS = (NNZ + CHUNK - 1) / CHUNK;   // 391
constexpr int ITERS   = CHUNK / 256;                 // 64
constexpr float THRESH = 0.01f;

// ---------- prep: per-neuron slope / softplus(bias) ----------
__global__ void k_precompute_sb(const int* __restrict__ gi,
                                const float* __restrict__ slope,
                                const float* __restrict__ raw_biases,
                                float* __restrict__ slopeN,
                                float* __restrict__ biasN) {
    int i = blockIdx.x * 256 + threadIdx.x;
    if (i < N) {
        int g = gi[i];
        slopeN[i] = slope[g];
        float rb = raw_biases[g];
        biasN[i] = (rb > 20.0f) ? rb : log1pf(expf(rb));   // softplus
    }
}

// ---------- pass 1: per-(bin,chunk) histogram ----------
__global__ void k_hist(const int* __restrict__ rows, unsigned* __restrict__ counts) {
    __shared__ unsigned hist[NBINS];
    int tid = threadIdx.x, chunk = blockIdx.x;
    for (int i = tid; i < NBINS; i += 256) hist[i] = 0;
    __syncthreads();
    int base = chunk * CHUNK;
    #pragma unroll 4
    for (int it = 0; it < ITERS; ++it) {
        int e = base + it * 256 + tid;
        if (e < NNZ) atomicAdd(&hist[((unsigned)rows[e]) >> BIN_BITS], 1u);
    }
    __syncthreads();
    for (int i = tid; i < NBINS; i += 256) counts[(size_t)i * NCHUNKS + chunk] = hist[i];
}

// ---------- pass 2a: per-bin exclusive scan across chunks ----------
__global__ void k_scan_chunks(unsigned* __restrict__ counts, unsigned* __restrict__ binTot) {
    int bin = blockIdx.x, lane = threadIdx.x;   // 64 threads
    unsigned carry = 0;
    for (int bse = 0; bse < NCHUNKS; bse += 64) {
        int idx = bse + lane;
        unsigned v = (idx < NCHUNKS) ? counts[(size_t)bin * NCHUNKS + idx] : 0u;
        unsigned x = v;
        #pragma unroll
        for (int off = 1; off < 64; off <<= 1) {
            unsigned y = __shfl_up(x, off, 64);
            if (lane >= off) x += y;
        }
        if (idx < NCHUNKS) counts[(size_t)bin * NCHUNKS + idx] = x - v + carry;
        carry += __shfl(x, 63, 64);
    }
    if (lane == 0) binTot[bin] = carry;
}

// ---------- pass 2b: exclusive scan over bins (single wave) ----------
__global__ void k_scan_bins(unsigned* __restrict__ binBase) {
    int lane = threadIdx.x;   // 64 threads, 1 block
    unsigned carry = 0;
    for (int bse = 0; bse < NBINS; bse += 64) {
        int idx = bse + lane;
        unsigned v = (idx < NBINS) ? binBase[idx] : 0u;
        unsigned x = v;
        #pragma unroll
        for (int off = 1; off < 64; off <<= 1) {
            unsigned y = __shfl_up(x, off, 64);
            if (lane >= off) x += y;
        }
        if (idx < NBINS) binBase[idx] = x - v + carry;
        carry += __shfl(x, 63, 64);
    }
    if (lane == 0) binBase[NBINS] = carry;   // == NNZ
}

// ---------- pass 3: scatter into packed binned format ----------
__global__ void k_scatter(const int* __restrict__ rows, const int* __restrict__ cols,
                          const float* __restrict__ vals,
                          const unsigned* __restrict__ binBase,
                          const unsigned* __restrict__ counts,
                          uint2* __restrict__ pk) {
    __shared__ unsigned cursor[NBINS];
    int tid = threadIdx.x, chunk = blockIdx.x;
    for (int i = tid; i < NBINS; i += 256)
        cursor[i] = binBase[i] + counts[(size_t)i * NCHUNKS + chunk];
    __syncthreads();
    int base = chunk * CHUNK;
    for (int it = 0; it < ITERS; ++it) {
        int e = base + it * 256 + tid;
        if (e < NNZ) {
            unsigned r = (unsigned)rows[e];
            unsigned c = (unsigned)cols[e];
            float    v = vals[e];
            unsigned bin = r >> BIN_BITS, lr = r & (BIN - 1);
            unsigned pos = atomicAdd(&cursor[bin], 1u);
            pk[pos] = make_uint2(__float_as_uint(v), c | (lr << 17));
        }
    }
}

// ---------- sensory injection (clip + scatter-add) ----------
__global__ void k_sensory(const float* __restrict__ inputs, const int* __restrict__ sidx,
                          float* __restrict__ F, int t) {
    int idx = blockIdx.x * 256 + threadIdx.x;
    if (idx < S * B) {
        int s = idx >> 3, b = idx & 7;
        float val = inputs[((size_t)b * S + s) * T + t];
        val = (val >= THRESH) ? fminf(val, 1.0f) : 0.0f;
        atomicAdd(&F[(size_t)sidx[s] * B + b], val);
    }
}

// ---------- main step: binned SpMM + activation ----------
__global__ void k_step(const uint2* __restrict__ pk,
                       const unsigned* __restrict__ binBase,
                       const float* __restrict__ Fin,
                       const float* __restrict__ slopeN,
                       const float* __restrict__ biasN,
                       float* __restrict__ Fout,
                       float* __restrict__ out, int t) {
    __shared__ float acc[B][BIN];    // 4 KB, SoA: bank = lr % 32
    int tid = threadIdx.x, bin = blockIdx.x;
    for (int i = tid; i < B * BIN; i += 256) ((float*)acc)[i] = 0.0f;
    __syncthreads();

    unsigned start = binBase[bin], end = binBase[bin + 1];
    for (unsigned e = start + tid; e < end; e += 256) {
        uint2 p = pk[e];
        float v = __uint_as_float(p.x);
        unsigned c  = p.y & 0x1FFFFu;
        unsigned lr = p.y >> 17;
        const float4* fx = (const float4*)(Fin + (size_t)c * B);
        float4 x0 = fx[0], x1 = fx[1];
        atomicAdd(&acc[0][lr], v * x0.x);
        atomicAdd(&acc[1][lr], v * x0.y);
        atomicAdd(&acc[2][lr], v * x0.z);
        atomicAdd(&acc[3][lr], v * x0.w);
        atomicAdd(&acc[4][lr], v * x1.x);
        atomicAdd(&acc[5][lr], v * x1.y);
        atomicAdd(&acc[6][lr], v * x1.z);
        atomicAdd(&acc[7][lr], v * x1.w);
    }
    __syncthreads();

    if (tid < BIN) {
        int row = bin * BIN + tid;
        if (row < N) {
            float sl = slopeN[row], bi = biasN[row];
            float o[B];
            #pragma unroll
            for (int b = 0; b < B; ++b) {
                float y = sl * acc[b][tid] + bi;
                y = (y >= THRESH) ? y : 0.0f;
                o[b] = tanhf(y);
            }
            float4* fo = (float4*)(Fout + (size_t)row * B);
            fo[0] = make_float4(o[0], o[1], o[2], o[3]);
            fo[1] = make_float4(o[4], o[5], o[6], o[7]);
            #pragma unroll
            for (int b = 0; b < B; ++b)
                out[((size_t)b * N + row) * T + t] = o[b];
        }
    }
}

static inline size_t align_up(size_t x, size_t a) { return (x + a - 1) & ~(a - 1); }

extern "C" void kernel_launch(void* const* d_in, const int* in_sizes, int n_in,
                              void* d_out, int out_size, void* d_ws, size_t ws_size,
                              hipStream_t stream) {
    const float* vals  = (const float*)d_in[0];
    const int*   rows  = (const int*)d_in[1];
    const int*   cols  = (const int*)d_in[2];
    const int*   sidx  = (const int*)d_in[3];
    const int*   gi    = (const int*)d_in[4];
    const float* slope = (const float*)d_in[5];
    const float* rawb  = (const float*)d_in[6];
    const float* inputs = (const float*)d_in[7];
    float* out = (float*)d_out;

    // workspace layout
    char* ws = (char*)d_ws;
    size_t off = 0;
    uint2*    pk      = (uint2*)(ws + off);    off = align_up(off + (size_t)NNZ * 8, 256);
    unsigned* counts  = (unsigned*)(ws + off); off = align_up(off + (size_t)NBINS * NCHUNKS * 4, 256);
    unsigned* binBase = (unsigned*)(ws + off); off = align_up(off + (size_t)(NBINS + 1) * 4, 256);
    float*    F0      = (float*)(ws + off);    off = align_up(off + (size_t)N * B * 4, 256);
    float*    F1      = (float*)(ws + off);    off = align_up(off + (size_t)N * B * 4, 256);
    float*    slopeN  = (float*)(ws + off);    off = align_up(off + (size_t)N * 4, 256);
    float*    biasN   = (float*)(ws + off);    off = align_up(off + (size_t)N * 4, 256);
    if (off > ws_size) return;   // workspace too small — will show as validation failure

    // prep
    k_precompute_sb<<<(N + 255) / 256, 256, 0, stream>>>(gi, slope, rawb, slopeN, biasN);
    // counting sort: hist -> scan chunks -> scan bins -> scatter
    k_hist<<<NCHUNKS, 256, 0, stream>>>(rows, counts);
    k_scan_chunks<<<NBINS, 64, 0, stream>>>(counts, binBase);
    k_scan_bins<<<1, 64, 0, stream>>>(binBase);
    k_scatter<<<NCHUNKS, 256, 0, stream>>>(rows, cols, vals, binBase, counts, pk);

    // t=0 state: zeros + sensory input
    hipMemsetAsync(F0, 0, (size_t)N * B * 4, stream);
    k_sensory<<<(S * B + 255) / 256, 256, 0, stream>>>(inputs, sidx, F0, 0);

    float* Fcur = F0;
    float* Fnxt = F1;
    for (int t = 0; t < T; ++t) {
        k_step<<<NBINS, 256, 0, stream>>>(pk, binBase, Fcur, slopeN, biasN, Fnxt, out, t);
        if (t + 1 < T)
            k_sensory<<<(S * B + 255) / 256, 256, 0, stream>>>(inputs, sidx, Fnxt, t + 1);
        float* tmp = Fcur; Fcur = Fnxt; Fnxt = tmp;
    }
}